// Round 11
// baseline (174.728 us; speedup 1.0000x reference)
//
#include <hip/hip_runtime.h>
#include <stdint.h>

#define NTOK 8192
#define DIM  1024
#define NE   8
#define NPAIR 28
#define OUTD 4096
#define MAXT16 539   // >= sum_p ceil(cnt_p/16): 512 + 27 worst case

typedef __attribute__((ext_vector_type(8))) short bf16x8;
typedef __attribute__((ext_vector_type(4))) float f32x4;

static __device__ __forceinline__ unsigned short f2bf(float f) {
    uint32_t u = __float_as_uint(f);
    u += 0x7fffu + ((u >> 16) & 1u);     // RNE
    return (unsigned short)(u >> 16);
}

// ---- K0: weight repacks to bf16 (+ zero pairCnt; runs FIRST) ----
// w1m[e][j][k][i]  i contiguous : 524288 elems
// w2m[e][k][l][j]  j contiguous : 1048576 elems
__global__ __launch_bounds__(256) void k_wm(const float* __restrict__ W1,
                                            const float* __restrict__ W2,
                                            unsigned short* __restrict__ w1m,
                                            unsigned short* __restrict__ w2m,
                                            int* __restrict__ pairCnt) {
    int t = blockIdx.x * 256 + threadIdx.x;
    if (blockIdx.x == 0 && threadIdx.x < 32) pairCnt[threadIdx.x] = 0;
    if (t < 524288) {
        int i = t & 31, k = (t >> 5) & 63, j = (t >> 11) & 31, e = (t >> 16) & 7;
        w1m[t] = f2bf(W1[(((j * 32 + i) * 64 + k) * 8) + e]);
    } else {
        int t2 = t - 524288;
        int j = t2 & 31, l = (t2 >> 5) & 63, k = (t2 >> 11) & 63, e = (t2 >> 17) & 7;
        w2m[t2] = f2bf(W2[(((e * 64 + k) * 32 + j) * 64) + l]);
    }
}

// ---- K1: gate (fp32) + pair bucketing ----
__global__ __launch_bounds__(256) void k_gate(const float* __restrict__ x,
                                              const float* __restrict__ Wg,
                                              int* __restrict__ pairCnt,
                                              int* __restrict__ bucket,
                                              float* __restrict__ wgt) {
    __shared__ float sWg[NE][DIM];
    int tid = threadIdx.x;
    #pragma unroll
    for (int u = 0; u < 8; ++u) {
        int idx = u * 1024 + tid * 4;
        *(float4*)&sWg[0][idx] = *(const float4*)&Wg[idx];
    }
    __syncthreads();
    int w = tid >> 6, lane = tid & 63;
    int tok = blockIdx.x * 4 + w;
    float acc[NE];
    #pragma unroll
    for (int e = 0; e < NE; ++e) acc[e] = 0.f;
    const float* xr = x + (size_t)tok * DIM;
    #pragma unroll
    for (int c = 0; c < 4; ++c) {
        float4 xv = *(const float4*)&xr[c * 256 + lane * 4];
        #pragma unroll
        for (int e = 0; e < NE; ++e) {
            float4 wv = *(const float4*)&sWg[e][c * 256 + lane * 4];
            acc[e] += xv.x * wv.x + xv.y * wv.y + xv.z * wv.z + xv.w * wv.w;
        }
    }
    #pragma unroll
    for (int e = 0; e < NE; ++e)
        #pragma unroll
        for (int off = 32; off > 0; off >>= 1)
            acc[e] += __shfl_xor(acc[e], off, 64);
    if (lane == 0) {
        int i1 = 0; float v1 = acc[0];
        for (int e = 1; e < NE; ++e) if (acc[e] > v1) { v1 = acc[e]; i1 = e; }
        int i2 = -1; float v2 = -3.4e38f;
        for (int e = 0; e < NE; ++e) { if (e == i1) continue; if (acc[e] > v2) { v2 = acc[e]; i2 = e; } }
        float ex = expf(v2 - v1);
        float s  = 1.f / (1.f + ex);
        float w1v = s + 1e-6f;
        float w2v = ex * s + 1e-6f;
        int ea = min(i1, i2), eb = max(i1, i2);
        float wa = (i1 < i2) ? w1v : w2v;
        float wb = (i1 < i2) ? w2v : w1v;
        wgt[tok * 2 + 0] = wa;
        wgt[tok * 2 + 1] = wb;
        int pid = ea * 7 - (ea * (ea - 1)) / 2 + (eb - ea - 1);
        int pos = atomicAdd(&pairCnt[pid], 1);
        bucket[pid * NTOK + pos] = tok;
    }
}

// ---- K2: slot -> token map + 16-token tile descriptors ----
__global__ __launch_bounds__(256) void k_slots(const int* __restrict__ pairCnt,
                                               const int* __restrict__ bucket,
                                               int* __restrict__ tokmap,
                                               int4* __restrict__ tileDesc) {
    int s = blockIdx.x * 256 + threadIdx.x;
    {
        int off = 0;
        for (int p = 0; p < NPAIR; ++p) {
            int c = pairCnt[p];
            if (s < off + c) { tokmap[s] = bucket[p * NTOK + (s - off)]; break; }
            off += c;
        }
    }
    if (s < MAXT16) {
        int4 d; d.x = -1; d.y = 0; d.z = 0; d.w = 0;
        int toff = 0, soff = 0;
        for (int q = 0; q < NPAIR; ++q) {
            int c = pairCnt[q];
            int nt = (c + 15) >> 4;
            if (d.x < 0 && s < toff + nt) {
                int lt = s - toff;
                d.x = q;
                d.y = soff + lt * 16;
                d.z = min(16, c - lt * 16);
            }
            toff += nt; soff += c;
        }
        tileDesc[s] = d;
    }
}

// ---- K3: gather x -> xg3[j][slot][i] bf16 (64-B rows), LDS transpose ----
__global__ __launch_bounds__(256) void k_xg3(const float* __restrict__ x,
                                             const int* __restrict__ tokmap,
                                             unsigned short* __restrict__ xg3) {
    __shared__ float tile[8][1056];                 // pad +1 per 32
    int s0 = blockIdx.x * 8;
    int tid = threadIdx.x;
    int r = tid >> 5, c = tid & 31;
    int tok = tokmap[s0 + r];
    const float* xr = x + (size_t)tok * DIM;
    #pragma unroll
    for (int u = 0; u < 8; ++u) {
        int d = u * 128 + c * 4;
        float4 v = *(const float4*)&xr[d];
        int d2 = d + (d >> 5);
        tile[r][d2 + 0] = v.x; tile[r][d2 + 1] = v.y;
        tile[r][d2 + 2] = v.z; tile[r][d2 + 3] = v.w;
    }
    __syncthreads();
    int sl = tid >> 5, j = tid & 31;
    float v[32];
    #pragma unroll
    for (int i = 0; i < 32; ++i) v[i] = tile[sl][i * 33 + j];
    unsigned short* orow = xg3 + ((size_t)j * NTOK + s0 + sl) * 32;
    #pragma unroll
    for (int ic = 0; ic < 4; ++ic) {
        uint4 pk;
        pk.x = (uint32_t)f2bf(v[ic * 8 + 0]) | ((uint32_t)f2bf(v[ic * 8 + 1]) << 16);
        pk.y = (uint32_t)f2bf(v[ic * 8 + 2]) | ((uint32_t)f2bf(v[ic * 8 + 3]) << 16);
        pk.z = (uint32_t)f2bf(v[ic * 8 + 4]) | ((uint32_t)f2bf(v[ic * 8 + 5]) << 16);
        pk.w = (uint32_t)f2bf(v[ic * 8 + 6]) | ((uint32_t)f2bf(v[ic * 8 + 7]) << 16);
        *(uint4*)(orow + ic * 8) = pk;
    }
}

// ---- K4: fused BTT — double-buffered LDS, 1 barrier/kb, kb-split x2 ----
// bid>>1 = 16-token tile, bid&1 = k-half (4 kb each). XCD = bid%8 -> even XCDs
// only touch k<32 slices of W1/W2 (halved L2 working set).
__global__ __launch_bounds__(256, 4) void k_fz(const unsigned short* __restrict__ w1m,
                                               const unsigned short* __restrict__ w2m,
                                               const unsigned short* __restrict__ xg3,
                                               const float* __restrict__ bias,
                                               const int* __restrict__ tokmap,
                                               const float* __restrict__ wgt,
                                               const int4* __restrict__ tileDesc,
                                               float* __restrict__ out) {
    __shared__ unsigned short zls[2][8][2][4][16][8];  // 32 KB: [buf][kk][e][joct][tslot][jj]

    int bid = blockIdx.x;
    int4 td = tileDesc[bid >> 1];
    int kb0 = (bid & 1) * 4;
    int p = td.x, s0 = td.y, cnt = td.z;
    if (p < 0) return;

    int a0 = 0, r0 = p;
    while (r0 >= 7 - a0) { r0 -= 7 - a0; ++a0; }
    int ea = a0, eb = a0 + 1 + r0;

    int tid = threadIdx.x;
    int w = tid >> 6, l = tid & 63;
    int lr = l & 15, lg = l >> 4;
    int e_lane = lr >> 3, kk = lr & 7;
    int my_e = e_lane ? eb : ea;

    // phase-1 gate scales (t = lg*4 + r, e = e_lane)
    float gs[4];
    #pragma unroll
    for (int r = 0; r < 4; ++r) {
        int tok = tokmap[min(s0 + lg * 4 + r, NTOK - 1)];
        float2 wv = *(const float2*)&wgt[tok * 2];
        gs[r] = e_lane ? wv.y : wv.x;
    }
    // phase-2 per-lane token (t = lr)
    int tok2 = tokmap[min(s0 + lr, NTOK - 1)];
    bool valid2 = lr < cnt;

    // x A-fragments for this wave's 8 j's (reused across all kb)
    bf16x8 a[8];
    int srow = min(s0 + lr, NTOK - 1);
    #pragma unroll
    for (int jj = 0; jj < 8; ++jj) {
        int j = w * 8 + jj;
        a[jj] = *(const bf16x8*)(xg3 + ((size_t)j * NTOK + srow) * 32 + lg * 8);
    }

    const f32x4 zero4 = {0.f, 0.f, 0.f, 0.f};

    // W1 frag base: w1m[my_e][w*8+jj][kb*8+kk][i: lg*8..]; jj stride 2048, kb stride 256
    const unsigned short* w1base = w1m + (((size_t)(my_e * 32 + w * 8) * 64) + kk) * 32 + lg * 8;

    bf16x8 w1f[8];
    #pragma unroll
    for (int jj = 0; jj < 8; ++jj)
        w1f[jj] = *(const bf16x8*)(w1base + (size_t)jj * 2048 + (size_t)kb0 * 256);

    // phase 1 for local kb n (uses w1f = frags(n)), writes zls[buf], prefetches frags(n+1)
    auto phase1 = [&](int n, int buf) {
        f32x4 dj[8];
        #pragma unroll
        for (int jj = 0; jj < 8; ++jj)
            dj[jj] = __builtin_amdgcn_mfma_f32_16x16x32_bf16(a[jj], w1f[jj], zero4, 0, 0, 0);
        if (n + 1 < 4) {
            #pragma unroll
            for (int jj = 0; jj < 8; ++jj)
                w1f[jj] = *(const bf16x8*)(w1base + (size_t)jj * 2048 + (size_t)(kb0 + n + 1) * 256);
        }
        #pragma unroll
        for (int r = 0; r < 4; ++r) {
            float g = gs[r];
            int ts = (lg * 4 + r) ^ kk;             // XOR swizzle (verified conflict-free)
            uint4 pk;
            pk.x = (uint32_t)f2bf(dj[0][r] * g) | ((uint32_t)f2bf(dj[1][r] * g) << 16);
            pk.y = (uint32_t)f2bf(dj[2][r] * g) | ((uint32_t)f2bf(dj[3][r] * g) << 16);
            pk.z = (uint32_t)f2bf(dj[4][r] * g) | ((uint32_t)f2bf(dj[5][r] * g) << 16);
            pk.w = (uint32_t)f2bf(dj[6][r] * g) | ((uint32_t)f2bf(dj[7][r] * g) << 16);
            *(uint4*)&zls[buf][kk][e_lane][w][ts][0] = pk;
        }
    };

    phase1(0, 0);
    __syncthreads();

    for (int kbl = 0; kbl < 4; ++kbl) {
        int buf = kbl & 1;
        if (kbl < 3) phase1(kbl + 1, buf ^ 1);      // fill other buffer (no barrier needed)

        // ---- phase 2 (kb = kb0+kbl): A = W2 (m=l), B = z (n=token) ----
        int kb = kb0 + kbl;
        #pragma unroll
        for (int k = 0; k < 8; ++k) {
            int kg = kb * 8 + k;
            bf16x8 az0 = *(const bf16x8*)&zls[buf][k][0][lg][lr ^ k][0];
            bf16x8 az1 = *(const bf16x8*)&zls[buf][k][1][lg][lr ^ k][0];
            bf16x8 b0 = *(const bf16x8*)(w2m + (((size_t)ea * 64 + kg) * 64 + w * 16 + lr) * 32 + lg * 8);
            bf16x8 b1 = *(const bf16x8*)(w2m + (((size_t)eb * 64 + kg) * 64 + w * 16 + lr) * 32 + lg * 8);
            f32x4 acc = __builtin_amdgcn_mfma_f32_16x16x32_bf16(b0, az0, zero4, 0, 0, 0);
            acc = __builtin_amdgcn_mfma_f32_16x16x32_bf16(b1, az1, acc, 0, 0, 0);
            // D: lane holds l = w*16 + lg*4 + r (r=0..3), token = tok2 -> one f32x4 store
            if (valid2) {
                f32x4 bv = *(const f32x4*)&bias[kg * 64 + w * 16 + lg * 4];
                f32x4 o = acc + bv;
                __builtin_nontemporal_store(o,
                    (f32x4*)(out + (size_t)tok2 * OUTD + (size_t)kg * 64 + w * 16 + lg * 4));
            }
        }
        if (kbl < 3) __syncthreads();
    }
}

extern "C" void kernel_launch(void* const* d_in, const int* in_sizes, int n_in,
                              void* d_out, int out_size, void* d_ws, size_t ws_size,
                              hipStream_t stream) {
    const float* x  = (const float*)d_in[0];
    const float* Wg = (const float*)d_in[1];
    const float* W1 = (const float*)d_in[2];
    const float* W2 = (const float*)d_in[3];
    const float* b  = (const float*)d_in[4];
    float* out = (float*)d_out;

    unsigned short* w1m = (unsigned short*)d_ws;            // 1 MB
    unsigned short* w2m = w1m + 524288;                     // 2 MB
    unsigned short* xg3 = w2m + 1048576;                    // 16 MB
    int*   tokmap   = (int*)(xg3 + 8388608);                // 8192 i
    float* wgt      = (float*)(tokmap + NTOK);              // 16384 f
    int*   pairCnt  = (int*)(wgt + 2 * NTOK);               // 32 i
    int4*  tileDesc = (int4*)(pairCnt + 32);                // 539 int4
    int*   bucket   = (int*)xg3;                            // aliased: dead before k_xg3 runs

    k_wm   <<<6144, 256, 0, stream>>>(W1, W2, w1m, w2m, pairCnt);
    k_gate <<<2048, 256, 0, stream>>>(x, Wg, pairCnt, bucket, wgt);
    k_slots<<<32,   256, 0, stream>>>(pairCnt, bucket, tokmap, tileDesc);
    k_xg3  <<<1024, 256, 0, stream>>>(x, tokmap, xg3);
    k_fz   <<<MAXT16 * 2, 256, 0, stream>>>(w1m, w2m, xg3, b, tokmap, wgt, tileDesc, out);
}

// Round 12
// 159.310 us; speedup vs baseline: 1.0968x; 1.0968x over previous
//
#include <hip/hip_runtime.h>
#include <stdint.h>

#define NTOK 8192
#define DIM  1024
#define NE   8
#define NPAIR 28
#define OUTD 4096
#define MAXT16 539   // >= sum_p ceil(cnt_p/16): 512 + 27 worst case

typedef __attribute__((ext_vector_type(8))) short bf16x8;
typedef __attribute__((ext_vector_type(4))) float f32x4;

static __device__ __forceinline__ unsigned short f2bf(float f) {
    uint32_t u = __float_as_uint(f);
    u += 0x7fffu + ((u >> 16) & 1u);     // RNE
    return (unsigned short)(u >> 16);
}

// ---- K0: weight repacks to bf16 (+ zero pairCnt; runs FIRST) ----
// w1m[e][j][k][i]  i contiguous : 524288 elems
// w2m[e][k][l][j]  j contiguous : 1048576 elems
__global__ __launch_bounds__(256) void k_wm(const float* __restrict__ W1,
                                            const float* __restrict__ W2,
                                            unsigned short* __restrict__ w1m,
                                            unsigned short* __restrict__ w2m,
                                            int* __restrict__ pairCnt) {
    int t = blockIdx.x * 256 + threadIdx.x;
    if (blockIdx.x == 0 && threadIdx.x < 32) pairCnt[threadIdx.x] = 0;
    if (t < 524288) {
        int i = t & 31, k = (t >> 5) & 63, j = (t >> 11) & 31, e = (t >> 16) & 7;
        w1m[t] = f2bf(W1[(((j * 32 + i) * 64 + k) * 8) + e]);
    } else {
        int t2 = t - 524288;
        int j = t2 & 31, l = (t2 >> 5) & 63, k = (t2 >> 11) & 63, e = (t2 >> 17) & 7;
        w2m[t2] = f2bf(W2[(((e * 64 + k) * 32 + j) * 64) + l]);
    }
}

// ---- K1: gate (fp32) + pair bucketing ----
__global__ __launch_bounds__(256) void k_gate(const float* __restrict__ x,
                                              const float* __restrict__ Wg,
                                              int* __restrict__ pairCnt,
                                              int* __restrict__ bucket,
                                              float* __restrict__ wgt) {
    __shared__ float sWg[NE][DIM];
    int tid = threadIdx.x;
    #pragma unroll
    for (int u = 0; u < 8; ++u) {
        int idx = u * 1024 + tid * 4;
        *(float4*)&sWg[0][idx] = *(const float4*)&Wg[idx];
    }
    __syncthreads();
    int w = tid >> 6, lane = tid & 63;
    int tok = blockIdx.x * 4 + w;
    float acc[NE];
    #pragma unroll
    for (int e = 0; e < NE; ++e) acc[e] = 0.f;
    const float* xr = x + (size_t)tok * DIM;
    #pragma unroll
    for (int c = 0; c < 4; ++c) {
        float4 xv = *(const float4*)&xr[c * 256 + lane * 4];
        #pragma unroll
        for (int e = 0; e < NE; ++e) {
            float4 wv = *(const float4*)&sWg[e][c * 256 + lane * 4];
            acc[e] += xv.x * wv.x + xv.y * wv.y + xv.z * wv.z + xv.w * wv.w;
        }
    }
    #pragma unroll
    for (int e = 0; e < NE; ++e)
        #pragma unroll
        for (int off = 32; off > 0; off >>= 1)
            acc[e] += __shfl_xor(acc[e], off, 64);
    if (lane == 0) {
        int i1 = 0; float v1 = acc[0];
        for (int e = 1; e < NE; ++e) if (acc[e] > v1) { v1 = acc[e]; i1 = e; }
        int i2 = -1; float v2 = -3.4e38f;
        for (int e = 0; e < NE; ++e) { if (e == i1) continue; if (acc[e] > v2) { v2 = acc[e]; i2 = e; } }
        float ex = expf(v2 - v1);
        float s  = 1.f / (1.f + ex);
        float w1v = s + 1e-6f;
        float w2v = ex * s + 1e-6f;
        int ea = min(i1, i2), eb = max(i1, i2);
        float wa = (i1 < i2) ? w1v : w2v;
        float wb = (i1 < i2) ? w2v : w1v;
        wgt[tok * 2 + 0] = wa;
        wgt[tok * 2 + 1] = wb;
        int pid = ea * 7 - (ea * (ea - 1)) / 2 + (eb - ea - 1);
        int pos = atomicAdd(&pairCnt[pid], 1);
        bucket[pid * NTOK + pos] = tok;
    }
}

// ---- K2: slot -> token map + 16-token tile descriptors ----
__global__ __launch_bounds__(256) void k_slots(const int* __restrict__ pairCnt,
                                               const int* __restrict__ bucket,
                                               int* __restrict__ tokmap,
                                               int4* __restrict__ tileDesc) {
    int s = blockIdx.x * 256 + threadIdx.x;
    {
        int off = 0;
        for (int p = 0; p < NPAIR; ++p) {
            int c = pairCnt[p];
            if (s < off + c) { tokmap[s] = bucket[p * NTOK + (s - off)]; break; }
            off += c;
        }
    }
    if (s < MAXT16) {
        int4 d; d.x = -1; d.y = 0; d.z = 0; d.w = 0;
        int toff = 0, soff = 0;
        for (int q = 0; q < NPAIR; ++q) {
            int c = pairCnt[q];
            int nt = (c + 15) >> 4;
            if (d.x < 0 && s < toff + nt) {
                int lt = s - toff;
                d.x = q;
                d.y = soff + lt * 16;
                d.z = min(16, c - lt * 16);
            }
            toff += nt; soff += c;
        }
        tileDesc[s] = d;
    }
}

// ---- K3: gather x -> xg3[j][slot][i] bf16 (64-B rows), LDS transpose ----
__global__ __launch_bounds__(256) void k_xg3(const float* __restrict__ x,
                                             const int* __restrict__ tokmap,
                                             unsigned short* __restrict__ xg3) {
    __shared__ float tile[8][1056];                 // pad +1 per 32
    int s0 = blockIdx.x * 8;
    int tid = threadIdx.x;
    int r = tid >> 5, c = tid & 31;
    int tok = tokmap[s0 + r];
    const float* xr = x + (size_t)tok * DIM;
    #pragma unroll
    for (int u = 0; u < 8; ++u) {
        int d = u * 128 + c * 4;
        float4 v = *(const float4*)&xr[d];
        int d2 = d + (d >> 5);
        tile[r][d2 + 0] = v.x; tile[r][d2 + 1] = v.y;
        tile[r][d2 + 2] = v.z; tile[r][d2 + 3] = v.w;
    }
    __syncthreads();
    int sl = tid >> 5, j = tid & 31;
    float v[32];
    #pragma unroll
    for (int i = 0; i < 32; ++i) v[i] = tile[sl][i * 33 + j];
    unsigned short* orow = xg3 + ((size_t)j * NTOK + s0 + sl) * 32;
    #pragma unroll
    for (int ic = 0; ic < 4; ++ic) {
        uint4 pk;
        pk.x = (uint32_t)f2bf(v[ic * 8 + 0]) | ((uint32_t)f2bf(v[ic * 8 + 1]) << 16);
        pk.y = (uint32_t)f2bf(v[ic * 8 + 2]) | ((uint32_t)f2bf(v[ic * 8 + 3]) << 16);
        pk.z = (uint32_t)f2bf(v[ic * 8 + 4]) | ((uint32_t)f2bf(v[ic * 8 + 5]) << 16);
        pk.w = (uint32_t)f2bf(v[ic * 8 + 6]) | ((uint32_t)f2bf(v[ic * 8 + 7]) << 16);
        *(uint4*)(orow + ic * 8) = pk;
    }
}

// ---- K4: fused BTT — LDS y-transpose epilogue: full-line token-row stores ----
// bid>>1 = 16-token tile, bid&1 = k-half (4 kb each).
__global__ __launch_bounds__(256, 3) void k_fz(const unsigned short* __restrict__ w1m,
                                               const unsigned short* __restrict__ w2m,
                                               const unsigned short* __restrict__ xg3,
                                               const float* __restrict__ bias,
                                               const int* __restrict__ tokmap,
                                               const float* __restrict__ wgt,
                                               const int4* __restrict__ tileDesc,
                                               float* __restrict__ out) {
    __shared__ unsigned short zls[8][2][4][16][8];  // 16 KB: [kk][e][joct][tslot][jj]
    __shared__ float ybuf[16][8][64];               // 32 KB: [t][k][l'] XOR-swizzled

    int bid = blockIdx.x;
    int4 td = tileDesc[bid >> 1];
    int kb0 = (bid & 1) * 4;
    int p = td.x, s0 = td.y, cnt = td.z;
    if (p < 0) return;

    int a0 = 0, r0 = p;
    while (r0 >= 7 - a0) { r0 -= 7 - a0; ++a0; }
    int ea = a0, eb = a0 + 1 + r0;

    int tid = threadIdx.x;
    int w = tid >> 6, l = tid & 63;
    int lr = l & 15, lg = l >> 4;
    int e_lane = lr >> 3, kk = lr & 7;
    int my_e = e_lane ? eb : ea;

    // phase-1 gate scales (t = lg*4 + r, e = e_lane)
    float gs[4];
    #pragma unroll
    for (int r = 0; r < 4; ++r) {
        int tok = tokmap[min(s0 + lg * 4 + r, NTOK - 1)];
        float2 wv = *(const float2*)&wgt[tok * 2];
        gs[r] = e_lane ? wv.y : wv.x;
    }
    // epilogue tokens: wave w owns t = w*4 + tt
    int tok4[4];
    #pragma unroll
    for (int tt = 0; tt < 4; ++tt)
        tok4[tt] = tokmap[min(s0 + w * 4 + tt, NTOK - 1)];

    // x A-fragments for this wave's 8 j's (reused across all kb)
    bf16x8 a[8];
    int srow = min(s0 + lr, NTOK - 1);
    #pragma unroll
    for (int jj = 0; jj < 8; ++jj) {
        int j = w * 8 + jj;
        a[jj] = *(const bf16x8*)(xg3 + ((size_t)j * NTOK + srow) * 32 + lg * 8);
    }

    const f32x4 zero4 = {0.f, 0.f, 0.f, 0.f};

    // W1 frag base: w1m[my_e][w*8+jj][kb*8+kk][i: lg*8..]; jj stride 2048, kb stride 256
    const unsigned short* w1base = w1m + (((size_t)(my_e * 32 + w * 8) * 64) + kk) * 32 + lg * 8;

    bf16x8 w1f[8];
    #pragma unroll
    for (int jj = 0; jj < 8; ++jj)
        w1f[jj] = *(const bf16x8*)(w1base + (size_t)jj * 2048 + (size_t)kb0 * 256);

    for (int kbl = 0; kbl < 4; ++kbl) {
        int kb = kb0 + kbl;

        // ---- phase 1: z for kb (wave w owns j-oct w); prefetch next W1 frags ----
        {
            f32x4 dj[8];
            #pragma unroll
            for (int jj = 0; jj < 8; ++jj)
                dj[jj] = __builtin_amdgcn_mfma_f32_16x16x32_bf16(a[jj], w1f[jj], zero4, 0, 0, 0);
            if (kbl < 3) {
                #pragma unroll
                for (int jj = 0; jj < 8; ++jj)
                    w1f[jj] = *(const bf16x8*)(w1base + (size_t)jj * 2048 + (size_t)(kb + 1) * 256);
            }
            #pragma unroll
            for (int r = 0; r < 4; ++r) {
                float g = gs[r];
                int ts = (lg * 4 + r) ^ kk;         // XOR swizzle
                uint4 pk;
                pk.x = (uint32_t)f2bf(dj[0][r] * g) | ((uint32_t)f2bf(dj[1][r] * g) << 16);
                pk.y = (uint32_t)f2bf(dj[2][r] * g) | ((uint32_t)f2bf(dj[3][r] * g) << 16);
                pk.z = (uint32_t)f2bf(dj[4][r] * g) | ((uint32_t)f2bf(dj[5][r] * g) << 16);
                pk.w = (uint32_t)f2bf(dj[6][r] * g) | ((uint32_t)f2bf(dj[7][r] * g) << 16);
                *(uint4*)&zls[kk][e_lane][w][ts][0] = pk;
            }
        }
        __syncthreads();

        // ---- phase 2: A = W2 (m=l), B = z (n=token); D -> ybuf (LDS) ----
        #pragma unroll
        for (int k = 0; k < 8; ++k) {
            int kg = kb * 8 + k;
            bf16x8 az0 = *(const bf16x8*)&zls[k][0][lg][lr ^ k][0];
            bf16x8 az1 = *(const bf16x8*)&zls[k][1][lg][lr ^ k][0];
            bf16x8 b0 = *(const bf16x8*)(w2m + (((size_t)ea * 64 + kg) * 64 + w * 16 + lr) * 32 + lg * 8);
            bf16x8 b1 = *(const bf16x8*)(w2m + (((size_t)eb * 64 + kg) * 64 + w * 16 + lr) * 32 + lg * 8);
            f32x4 acc = __builtin_amdgcn_mfma_f32_16x16x32_bf16(b0, az0, zero4, 0, 0, 0);
            acc = __builtin_amdgcn_mfma_f32_16x16x32_bf16(b1, az1, acc, 0, 0, 0);
            // lane holds token = lr, l = w*16 + lg*4 .. +3 ; swizzle bits 4-5 by lr&3
            int lp = (w * 16 + lg * 4) ^ ((lr & 3) << 4);
            *(f32x4*)&ybuf[lr][k][lp] = acc;
        }
        __syncthreads();

        // ---- epilogue: wave-uniform token, 1 KB contiguous per store pair ----
        {
            // bias for this kb: 512 consecutive floats; lane i covers i*8..i*8+7
            f32x4 bv0 = *(const f32x4*)&bias[kb * 512 + l * 8];
            f32x4 bv1 = *(const f32x4*)&bias[kb * 512 + l * 8 + 4];
            #pragma unroll
            for (int tt = 0; tt < 4; ++tt) {
                int t = w * 4 + tt;
                if (t < cnt) {
                    int kq = l >> 3;
                    int lp = ((l & 7) * 8) ^ ((t & 3) << 4);
                    f32x4 y0 = *(const f32x4*)&ybuf[t][kq][lp];
                    f32x4 y1 = *(const f32x4*)&ybuf[t][kq][lp + 4];
                    f32x4 o0 = y0 + bv0;
                    f32x4 o1 = y1 + bv1;
                    float* dst = out + (size_t)tok4[tt] * OUTD + kb * 512 + l * 8;
                    __builtin_nontemporal_store(o0, (f32x4*)dst);
                    __builtin_nontemporal_store(o1, (f32x4*)(dst + 4));
                }
            }
        }
        if (kbl < 3) __syncthreads();               // protect zls/ybuf before next round
    }
}

extern "C" void kernel_launch(void* const* d_in, const int* in_sizes, int n_in,
                              void* d_out, int out_size, void* d_ws, size_t ws_size,
                              hipStream_t stream) {
    const float* x  = (const float*)d_in[0];
    const float* Wg = (const float*)d_in[1];
    const float* W1 = (const float*)d_in[2];
    const float* W2 = (const float*)d_in[3];
    const float* b  = (const float*)d_in[4];
    float* out = (float*)d_out;

    unsigned short* w1m = (unsigned short*)d_ws;            // 1 MB
    unsigned short* w2m = w1m + 524288;                     // 2 MB
    unsigned short* xg3 = w2m + 1048576;                    // 16 MB
    int*   tokmap   = (int*)(xg3 + 8388608);                // 8192 i
    float* wgt      = (float*)(tokmap + NTOK);              // 16384 f
    int*   pairCnt  = (int*)(wgt + 2 * NTOK);               // 32 i
    int4*  tileDesc = (int4*)(pairCnt + 32);                // 539 int4
    int*   bucket   = (int*)xg3;                            // aliased: dead before k_xg3 runs

    k_wm   <<<6144, 256, 0, stream>>>(W1, W2, w1m, w2m, pairCnt);
    k_gate <<<2048, 256, 0, stream>>>(x, Wg, pairCnt, bucket, wgt);
    k_slots<<<32,   256, 0, stream>>>(pairCnt, bucket, tokmap, tileDesc);
    k_xg3  <<<1024, 256, 0, stream>>>(x, tokmap, xg3);
    k_fz   <<<MAXT16 * 2, 256, 0, stream>>>(w1m, w2m, xg3, b, tokmap, wgt, tileDesc, out);
}